// Round 8
// baseline (264.503 us; speedup 1.0000x reference)
//
#include <hip/hip_runtime.h>

// CoLL fully fused, ONE dispatch, hand-rolled device barrier.
// y(p,c) = sum_{3x3} w[dq] * x(q,c) * co[bin(p,c), bin(q,c)]
// N=8, H=128, W=128, C=64, NUM_BINS=8. One image = 128*128*16 = 262144 float4.
// Grid 1024x256 (4 blocks/CU, co-resident by construction); each thread owns one
// within-image float4 offset across all 8 images.

static constexpr int IMG4 = 128 * 128 * 16;
static constexpr int NBLK = 1024, NTHR = 256;
static constexpr int GROUPS = 32;              // split atomics across 32 lines
static constexpr int ARRIVALS = NBLK / GROUPS; // 32 per group
static constexpr int LSTRIDE = 32;             // 32 uints = 128 B per line
// d_ws layout (uint idx): minkey g*32 | negmaxkey 1024+g*32 | cnt 2048+g*32
static constexpr unsigned CNT_TARGET = 0xFFFFFFFFu - (unsigned)ARRIVALS;

__device__ __forceinline__ unsigned f2key(float f) {
    unsigned u = __float_as_uint(f);
    return (u & 0x80000000u) ? ~u : (u | 0x80000000u);
}
__device__ __forceinline__ float key2f(unsigned k) {
    unsigned u = (k & 0x80000000u) ? (k & 0x7FFFFFFFu) : ~k;
    return __uint_as_float(u);
}
__device__ __forceinline__ int qbin(float v, float xmin, float scale) {
    float t = (v - xmin) * scale;   // >= 0 exactly
    t = fminf(t, 7.0f);
    return (int)t;                  // trunc == floor for t >= 0
}

__global__ __launch_bounds__(256, 4) void fused_k(
        const float4* __restrict__ x4, const float* __restrict__ co,
        const float* __restrict__ wsp, float4* __restrict__ y4,
        unsigned* __restrict__ ws) {

    __shared__ float co_s[64], w_s[9], cw[9 * 64];
    __shared__ float sred[8];
    __shared__ unsigned skey[64];   // [0..31] minkeys, [32..63] negmax keys

    const int ofs = blockIdx.x * 256 + threadIdx.x;  // within-image float4 idx
    const int wid = threadIdx.x >> 6, lane = threadIdx.x & 63;

    // ---- phase 1: load slice (kept in registers), block min/max ----
    float4 v[8];
#pragma unroll
    for (int k = 0; k < 8; ++k) v[k] = x4[k * IMG4 + ofs];

    if (threadIdx.x < 64) co_s[threadIdx.x] = co[threadIdx.x];
    if (threadIdx.x < 9)  w_s[threadIdx.x] = wsp[threadIdx.x];
    __syncthreads();
    for (int idx = threadIdx.x; idx < 576; idx += 256)
        cw[idx] = w_s[idx >> 6] * co_s[idx & 63];

    float lmin = v[0].x, lmax = v[0].x;
#pragma unroll
    for (int k = 0; k < 8; ++k) {
        lmin = fminf(lmin, fminf(fminf(v[k].x, v[k].y), fminf(v[k].z, v[k].w)));
        lmax = fmaxf(lmax, fmaxf(fmaxf(v[k].x, v[k].y), fmaxf(v[k].z, v[k].w)));
    }
#pragma unroll
    for (int off = 32; off; off >>= 1) {
        lmin = fminf(lmin, __shfl_xor(lmin, off, 64));
        lmax = fmaxf(lmax, __shfl_xor(lmax, off, 64));
    }
    if (lane == 0) { sred[wid] = lmin; sred[4 + wid] = lmax; }
    __syncthreads();   // cw + sred ready

    const int g = blockIdx.x & (GROUPS - 1);
    if (threadIdx.x == 0) {
        float bmin = fminf(fminf(sred[0], sred[1]), fminf(sred[2], sred[3]));
        float bmax = fmaxf(fmaxf(sred[4], sred[5]), fmaxf(sred[6], sred[7]));
        atomicMin(&ws[g * LSTRIDE], f2key(bmin));
        atomicMin(&ws[1024 + g * LSTRIDE], ~f2key(bmax));  // max as min of ~key
        __threadfence();                                   // release
        atomicSub(&ws[2048 + g * LSTRIDE], 1u);            // arrive (init 0xFF..)
    }

    // ---- device barrier: thread t<32 spins on group t's countdown ----
    if (threadIdx.x < 32) {
        unsigned spins = 0;
        while (__hip_atomic_load(&ws[2048 + threadIdx.x * LSTRIDE],
                                 __ATOMIC_RELAXED, __HIP_MEMORY_SCOPE_AGENT)
                   != CNT_TARGET &&
               spins < (1u << 26)) ++spins;   // safety valve: wrong, not hung
    }
    __threadfence();   // acquire side
    __syncthreads();

    if (threadIdx.x < 32) {
        skey[threadIdx.x] = __hip_atomic_load(&ws[threadIdx.x * LSTRIDE],
                                              __ATOMIC_RELAXED,
                                              __HIP_MEMORY_SCOPE_AGENT);
        skey[32 + threadIdx.x] = __hip_atomic_load(&ws[1024 + threadIdx.x * LSTRIDE],
                                                   __ATOMIC_RELAXED,
                                                   __HIP_MEMORY_SCOPE_AGENT);
    }
    __syncthreads();

    unsigned mk = skey[0], nk = skey[32];
#pragma unroll
    for (int i = 1; i < 32; ++i) {
        mk = min(mk, skey[i]);
        nk = min(nk, skey[32 + i]);
    }
    const float xmin = key2f(mk);
    const float xmax = key2f(~nk);
    const float scale = 8.0f / ((xmax - xmin) + 1e-8f);

    // ---- phase 2: fused 3x3 stencil + co-occurrence gather ----
    const int w = (ofs >> 4) & 127;
    const int h = (ofs >> 11) & 127;
    const bool wm = (w > 0), wp = (w < 127), hm = (h > 0), hp = (h < 127);

#pragma unroll 2
    for (int k = 0; k < 8; ++k) {
        const int base = k * IMG4 + ofs;
        const float4 xc = v[k];
        const int bx = qbin(xc.x, xmin, scale), ipx = bx * 8;
        const int by = qbin(xc.y, xmin, scale), ipy = by * 8;
        const int bz = qbin(xc.z, xmin, scale), ipz = bz * 8;
        const int bw = qbin(xc.w, xmin, scale), ipw = bw * 8;

        // center tap (t=4): col bin == row bin
        float ax = xc.x * cw[4 * 64 + ipx + bx];
        float ay = xc.y * cw[4 * 64 + ipy + by];
        float az = xc.z * cw[4 * 64 + ipz + bz];
        float aw = xc.w * cw[4 * 64 + ipw + bw];

#define TAP(T, OFF) { \
        const float4 q = x4[base + (OFF)]; \
        ax = fmaf(q.x, cw[(T) * 64 + ipx + qbin(q.x, xmin, scale)], ax); \
        ay = fmaf(q.y, cw[(T) * 64 + ipy + qbin(q.y, xmin, scale)], ay); \
        az = fmaf(q.z, cw[(T) * 64 + ipz + qbin(q.z, xmin, scale)], az); \
        aw = fmaf(q.w, cw[(T) * 64 + ipw + qbin(q.w, xmin, scale)], aw); }

        if (hm && wm) TAP(0, -2064)
        if (hm)       TAP(1, -2048)
        if (hm && wp) TAP(2, -2032)
        if (wm)       TAP(3, -16)
        if (wp)       TAP(5,  16)
        if (hp && wm) TAP(6,  2032)
        if (hp)       TAP(7,  2048)
        if (hp && wp) TAP(8,  2064)
#undef TAP

        y4[base] = make_float4(ax, ay, az, aw);
    }
}

extern "C" void kernel_launch(void* const* d_in, const int* in_sizes, int n_in,
                              void* d_out, int out_size, void* d_ws, size_t ws_size,
                              hipStream_t stream) {
    const float4* x4 = (const float4*)d_in[0];
    const float*  co = (const float*)d_in[1];
    const float*  wsp = (const float*)d_in[2];
    float4* y4 = (float4*)d_out;
    unsigned* ws = (unsigned*)d_ws;

    // 0xFF init covers: minkeys (0xFFFFFFFF), negmax keys (min-reduced), and
    // countdown counters (0xFFFFFFFF - 32 target). 3 regions x 1024 uints.
    hipMemsetAsync(d_ws, 0xFF, 3 * 1024 * sizeof(unsigned), stream);
    hipLaunchKernelGGL(fused_k, dim3(NBLK), dim3(NTHR), 0, stream,
                       x4, co, wsp, y4, ws);
}

// Round 9
// 111.514 us; speedup vs baseline: 2.3719x; 2.3719x over previous
//
#include <hip/hip_runtime.h>

// CoLL fused, 2 dispatches, NO atomics (R7 structure + XCD swizzle):
//  A) reduce_k : per-block min/max partials -> d_ws (2048 float2)
//  B) coll_k   : redundant partial-reduce prologue, then fused 3x3 stencil
//     y(p,c) = sum_{3x3} w[dq] * x(q,c) * co[bin(p,c), bin(q,c)]
// N=8, H=128, W=128, C=64, NUM_BINS=8. One image = 128*128*16 = 262144 float4.

static constexpr int IMG4 = 128 * 128 * 16;
static constexpr int TOT4 = 8 * IMG4;            // 2097152 float4
static constexpr int RBLK = 2048;                // reduce blocks
static constexpr int RSTRIDE = RBLK * 256;       // 524288; TOT4/RSTRIDE = 4
static constexpr int NBLK = 1024, NTHR = 256;    // coll grid: NBLK*NTHR == IMG4

__device__ __forceinline__ int qbin(float v, float xmin, float scale) {
    float t = (v - xmin) * scale;   // >= 0 exactly (v >= xmin in f32)
    t = fminf(t, 7.0f);
    return (int)t;                  // trunc == floor for t >= 0
}

__global__ __launch_bounds__(256) void reduce_k(const float4* __restrict__ x4,
                                                float2* __restrict__ part) {
    const int i = blockIdx.x * 256 + threadIdx.x;
    float4 a = x4[i];
    float4 b = x4[i + RSTRIDE];
    float4 c = x4[i + 2 * RSTRIDE];
    float4 d = x4[i + 3 * RSTRIDE];
    float lmin = fminf(fminf(fminf(a.x, a.y), fminf(a.z, a.w)),
                       fminf(fminf(b.x, b.y), fminf(b.z, b.w)));
    float lmax = fmaxf(fmaxf(fmaxf(a.x, a.y), fmaxf(a.z, a.w)),
                       fmaxf(fmaxf(b.x, b.y), fmaxf(b.z, b.w)));
    lmin = fminf(lmin, fminf(fminf(fminf(c.x, c.y), fminf(c.z, c.w)),
                             fminf(fminf(d.x, d.y), fminf(d.z, d.w))));
    lmax = fmaxf(lmax, fmaxf(fmaxf(fmaxf(c.x, c.y), fmaxf(c.z, c.w)),
                             fmaxf(fmaxf(d.x, d.y), fmaxf(d.z, d.w))));
#pragma unroll
    for (int off = 32; off; off >>= 1) {
        lmin = fminf(lmin, __shfl_xor(lmin, off, 64));
        lmax = fmaxf(lmax, __shfl_xor(lmax, off, 64));
    }
    __shared__ float smin[4], smax[4];
    const int wid = threadIdx.x >> 6, lane = threadIdx.x & 63;
    if (lane == 0) { smin[wid] = lmin; smax[wid] = lmax; }
    __syncthreads();
    if (threadIdx.x == 0) {
        part[blockIdx.x] = make_float2(
            fminf(fminf(smin[0], smin[1]), fminf(smin[2], smin[3])),
            fmaxf(fmaxf(smax[0], smax[1]), fmaxf(smax[2], smax[3])));
    }
}

__global__ __launch_bounds__(256) void coll_k(const float4* __restrict__ x4,
                                              const float* __restrict__ co,
                                              const float* __restrict__ wsp,
                                              float4* __restrict__ y4,
                                              const float2* __restrict__ part) {
    __shared__ float co_s[64], w_s[9];
    __shared__ float cw[9 * 64];   // pre-multiplied w_spatial[tap] * co[row][col]
    __shared__ float sred[8];      // [0..3] wave mins, [4..7] wave maxs

    if (threadIdx.x < 64) co_s[threadIdx.x] = co[threadIdx.x];
    if (threadIdx.x < 9)  w_s[threadIdx.x] = wsp[threadIdx.x];

    // prologue: every block redundantly reduces the 2048 partials (16 KB, L2-hot)
    float gmin = 3.4028235e38f, gmax = -3.4028235e38f;
#pragma unroll
    for (int j = 0; j < 8; ++j) {
        float2 p = part[threadIdx.x * 8 + j];
        gmin = fminf(gmin, p.x);
        gmax = fmaxf(gmax, p.y);
    }
#pragma unroll
    for (int off = 32; off; off >>= 1) {
        gmin = fminf(gmin, __shfl_xor(gmin, off, 64));
        gmax = fmaxf(gmax, __shfl_xor(gmax, off, 64));
    }
    const int wid = threadIdx.x >> 6, lane = threadIdx.x & 63;
    if (lane == 0) { sred[wid] = gmin; sred[4 + wid] = gmax; }
    __syncthreads();   // co_s, w_s, sred all visible

    for (int idx = threadIdx.x; idx < 576; idx += 256)
        cw[idx] = w_s[idx >> 6] * co_s[idx & 63];

    const float xmin = fminf(fminf(sred[0], sred[1]), fminf(sred[2], sred[3]));
    const float xmax = fmaxf(fmaxf(sred[4], sred[5]), fmaxf(sred[6], sred[7]));
    const float scale = 8.0f / ((xmax - xmin) + 1e-8f);
    __syncthreads();   // cw ready

    // XCD-aware bijective swizzle (1024 = 8 XCD x 128): blocks with adjacent
    // ofs (sharing stencil halo rows) land on the same XCD's L2.
    const int swz = (blockIdx.x & 7) * 128 + (blockIdx.x >> 3);
    const int ofs = swz * 256 + threadIdx.x;       // within-image float4 idx
    const int w = (ofs >> 4) & 127;
    const int h = (ofs >> 11) & 127;
    const bool wm = (w > 0), wp = (w < 127), hm = (h > 0), hp = (h < 127);

#pragma unroll 2
    for (int k = 0; k < 8; ++k) {
        const int base = k * IMG4 + ofs;
        const float4 xc = x4[base];
        const int bx = qbin(xc.x, xmin, scale), ipx = bx * 8;
        const int by = qbin(xc.y, xmin, scale), ipy = by * 8;
        const int bz = qbin(xc.z, xmin, scale), ipz = bz * 8;
        const int bw = qbin(xc.w, xmin, scale), ipw = bw * 8;

        // center tap (t=4): col bin == row bin
        float ax = xc.x * cw[4 * 64 + ipx + bx];
        float ay = xc.y * cw[4 * 64 + ipy + by];
        float az = xc.z * cw[4 * 64 + ipz + bz];
        float aw = xc.w * cw[4 * 64 + ipw + bw];

#define TAP(T, OFF) { \
        const float4 q = x4[base + (OFF)]; \
        ax = fmaf(q.x, cw[(T) * 64 + ipx + qbin(q.x, xmin, scale)], ax); \
        ay = fmaf(q.y, cw[(T) * 64 + ipy + qbin(q.y, xmin, scale)], ay); \
        az = fmaf(q.z, cw[(T) * 64 + ipz + qbin(q.z, xmin, scale)], az); \
        aw = fmaf(q.w, cw[(T) * 64 + ipw + qbin(q.w, xmin, scale)], aw); }

        if (hm && wm) TAP(0, -2064)
        if (hm)       TAP(1, -2048)
        if (hm && wp) TAP(2, -2032)
        if (wm)       TAP(3, -16)
        if (wp)       TAP(5,  16)
        if (hp && wm) TAP(6,  2032)
        if (hp)       TAP(7,  2048)
        if (hp && wp) TAP(8,  2064)
#undef TAP

        y4[base] = make_float4(ax, ay, az, aw);
    }
}

extern "C" void kernel_launch(void* const* d_in, const int* in_sizes, int n_in,
                              void* d_out, int out_size, void* d_ws, size_t ws_size,
                              hipStream_t stream) {
    const float4* x4 = (const float4*)d_in[0];
    const float*  co = (const float*)d_in[1];
    const float*  wsp = (const float*)d_in[2];
    float4* y4 = (float4*)d_out;
    float2* part = (float2*)d_ws;    // 2048 float2 = 16 KB scratch

    hipLaunchKernelGGL(reduce_k, dim3(RBLK), dim3(NTHR), 0, stream, x4, part);
    hipLaunchKernelGGL(coll_k, dim3(NBLK), dim3(NTHR), 0, stream,
                       x4, co, wsp, y4, part);
}

// Round 10
// 101.601 us; speedup vs baseline: 2.6034x; 1.0976x over previous
//
#include <hip/hip_runtime.h>

// CoLL fused, 2 dispatches, NO atomics:
//  A) reduce_k : per-block min/max partials -> d_ws (2048 float2)
//  B) coll_k   : partial-reduce prologue, then fused 3x3 stencil with
//     branchless taps (clamped address + zero cw row) and batched loads.
//     y(p,c) = sum_{3x3} w[dq] * x(q,c) * co[bin(p,c), bin(q,c)]
// N=8, H=128, W=128, C=64, NUM_BINS=8. One image = 128*128*16 = 262144 float4.

static constexpr int IMG4 = 128 * 128 * 16;
static constexpr int TOT4 = 8 * IMG4;            // 2097152 float4
static constexpr int RBLK = 2048;                // reduce blocks
static constexpr int RSTRIDE = RBLK * 256;       // 524288; TOT4/RSTRIDE = 4
static constexpr int NBLK = 1024, NTHR = 256;    // coll grid: NBLK*NTHR == IMG4
static constexpr int ZROW = 576;                 // zeroed cw row for invalid taps

__device__ __forceinline__ int qbin(float v, float xmin, float scale) {
    float t = (v - xmin) * scale;   // >= 0 exactly (v >= xmin in f32)
    t = fminf(t, 7.0f);
    return (int)t;                  // trunc == floor for t >= 0
}

__global__ __launch_bounds__(256) void reduce_k(const float4* __restrict__ x4,
                                                float2* __restrict__ part) {
    const int i = blockIdx.x * 256 + threadIdx.x;
    float4 a = x4[i];
    float4 b = x4[i + RSTRIDE];
    float4 c = x4[i + 2 * RSTRIDE];
    float4 d = x4[i + 3 * RSTRIDE];
    float lmin = fminf(fminf(fminf(a.x, a.y), fminf(a.z, a.w)),
                       fminf(fminf(b.x, b.y), fminf(b.z, b.w)));
    float lmax = fmaxf(fmaxf(fmaxf(a.x, a.y), fmaxf(a.z, a.w)),
                       fmaxf(fmaxf(b.x, b.y), fmaxf(b.z, b.w)));
    lmin = fminf(lmin, fminf(fminf(fminf(c.x, c.y), fminf(c.z, c.w)),
                             fminf(fminf(d.x, d.y), fminf(d.z, d.w))));
    lmax = fmaxf(lmax, fmaxf(fmaxf(fmaxf(c.x, c.y), fmaxf(c.z, c.w)),
                             fmaxf(fmaxf(d.x, d.y), fmaxf(d.z, d.w))));
#pragma unroll
    for (int off = 32; off; off >>= 1) {
        lmin = fminf(lmin, __shfl_xor(lmin, off, 64));
        lmax = fmaxf(lmax, __shfl_xor(lmax, off, 64));
    }
    __shared__ float smin[4], smax[4];
    const int wid = threadIdx.x >> 6, lane = threadIdx.x & 63;
    if (lane == 0) { smin[wid] = lmin; smax[wid] = lmax; }
    __syncthreads();
    if (threadIdx.x == 0) {
        part[blockIdx.x] = make_float2(
            fminf(fminf(smin[0], smin[1]), fminf(smin[2], smin[3])),
            fmaxf(fmaxf(smax[0], smax[1]), fmaxf(smax[2], smax[3])));
    }
}

__global__ __launch_bounds__(256) void coll_k(const float4* __restrict__ x4,
                                              const float* __restrict__ co,
                                              const float* __restrict__ wsp,
                                              float4* __restrict__ y4,
                                              const float2* __restrict__ part) {
    __shared__ float co_s[64], w_s[9];
    __shared__ float cw[640];      // rows 0..8: w[tap]*co[r][c]; row 9: zeros
    __shared__ float sred[8];

    if (threadIdx.x < 64) co_s[threadIdx.x] = co[threadIdx.x];
    if (threadIdx.x < 9)  w_s[threadIdx.x] = wsp[threadIdx.x];

    // prologue: every block redundantly reduces the 2048 partials (16 KB, L2-hot)
    float gmin = 3.4028235e38f, gmax = -3.4028235e38f;
#pragma unroll
    for (int j = 0; j < 8; ++j) {
        float2 p = part[threadIdx.x * 8 + j];
        gmin = fminf(gmin, p.x);
        gmax = fmaxf(gmax, p.y);
    }
#pragma unroll
    for (int off = 32; off; off >>= 1) {
        gmin = fminf(gmin, __shfl_xor(gmin, off, 64));
        gmax = fmaxf(gmax, __shfl_xor(gmax, off, 64));
    }
    const int wid = threadIdx.x >> 6, lane = threadIdx.x & 63;
    if (lane == 0) { sred[wid] = gmin; sred[4 + wid] = gmax; }
    __syncthreads();

#pragma unroll
    for (int idx = threadIdx.x; idx < 640; idx += 256)
        cw[idx] = (idx < 576) ? w_s[idx >> 6] * co_s[idx & 63] : 0.0f;

    const float xmin = fminf(fminf(sred[0], sred[1]), fminf(sred[2], sred[3]));
    const float xmax = fmaxf(fmaxf(sred[4], sred[5]), fmaxf(sred[6], sred[7]));
    const float scale = 8.0f / ((xmax - xmin) + 1e-8f);
    __syncthreads();   // cw ready

    const int ofs = blockIdx.x * 256 + threadIdx.x;  // within-image float4 idx
    const int w = (ofs >> 4) & 127;
    const int h = (ofs >> 11) & 127;
    const bool wm = (w > 0), wp = (w < 127), hm = (h > 0), hp = (h < 127);

    // per-tap validity and gather-row (ZROW = zeros for out-of-bounds taps)
    const bool v0 = hm && wm, v1 = hm, v2 = hm && wp;
    const bool v3 = wm,                v5 = wp;
    const bool v6 = hp && wm, v7 = hp, v8 = hp && wp;
    const int r0 = v0 ? 0 * 64 : ZROW, r1 = v1 ? 1 * 64 : ZROW;
    const int r2 = v2 ? 2 * 64 : ZROW, r3 = v3 ? 3 * 64 : ZROW;
    const int r5 = v5 ? 5 * 64 : ZROW, r6 = v6 ? 6 * 64 : ZROW;
    const int r7 = v7 ? 7 * 64 : ZROW, r8 = v8 ? 8 * 64 : ZROW;

#pragma unroll 1
    for (int k = 0; k < 8; ++k) {
        const int base = k * IMG4 + ofs;

        // ---- phase A: issue all 9 loads (branchless, clamped) ----
        const float4 qc = x4[base];
        const float4 q0 = x4[v0 ? base - 2064 : base];
        const float4 q1 = x4[v1 ? base - 2048 : base];
        const float4 q2 = x4[v2 ? base - 2032 : base];
        const float4 q3 = x4[v3 ? base - 16   : base];
        const float4 q5 = x4[v5 ? base + 16   : base];
        const float4 q6 = x4[v6 ? base + 2032 : base];
        const float4 q7 = x4[v7 ? base + 2048 : base];
        const float4 q8 = x4[v8 ? base + 2064 : base];

        // ---- phase B: center bins (rows of cw within each tap block) ----
        const int bx = qbin(qc.x, xmin, scale), ipx = bx * 8;
        const int by = qbin(qc.y, xmin, scale), ipy = by * 8;
        const int bz = qbin(qc.z, xmin, scale), ipz = bz * 8;
        const int bw = qbin(qc.w, xmin, scale), ipw = bw * 8;

        float ax = qc.x * cw[4 * 64 + ipx + bx];
        float ay = qc.y * cw[4 * 64 + ipy + by];
        float az = qc.z * cw[4 * 64 + ipz + bz];
        float aw = qc.w * cw[4 * 64 + ipw + bw];

#define ACC(Q, R) { \
        ax = fmaf(Q.x, cw[(R) + ipx + qbin(Q.x, xmin, scale)], ax); \
        ay = fmaf(Q.y, cw[(R) + ipy + qbin(Q.y, xmin, scale)], ay); \
        az = fmaf(Q.z, cw[(R) + ipz + qbin(Q.z, xmin, scale)], az); \
        aw = fmaf(Q.w, cw[(R) + ipw + qbin(Q.w, xmin, scale)], aw); }

        ACC(q0, r0) ACC(q1, r1) ACC(q2, r2)
        ACC(q3, r3)             ACC(q5, r5)
        ACC(q6, r6) ACC(q7, r7) ACC(q8, r8)
#undef ACC

        y4[base] = make_float4(ax, ay, az, aw);
    }
}

extern "C" void kernel_launch(void* const* d_in, const int* in_sizes, int n_in,
                              void* d_out, int out_size, void* d_ws, size_t ws_size,
                              hipStream_t stream) {
    const float4* x4 = (const float4*)d_in[0];
    const float*  co = (const float*)d_in[1];
    const float*  wsp = (const float*)d_in[2];
    float4* y4 = (float4*)d_out;
    float2* part = (float2*)d_ws;    // 2048 float2 = 16 KB scratch

    hipLaunchKernelGGL(reduce_k, dim3(RBLK), dim3(NTHR), 0, stream, x4, part);
    hipLaunchKernelGGL(coll_k, dim3(NBLK), dim3(NTHR), 0, stream,
                       x4, co, wsp, y4, part);
}